// Round 1
// baseline (816.345 us; speedup 1.0000x reference)
//
#include <hip/hip_runtime.h>
#include <hip/hip_bf16.h>
#include <stdint.h>

// SpatioConvLayer: out = relu(x + b + einsum('iok,knm,bitm->botn', theta, Lk, x))
// Plan: (1) BT[n][k*1024+m] = bf16(Lk[k][n][m]); (2) Y[(b*48+t)*64+o][k*1024+m]
//       = sum_i theta[i,o,k] * x[b,i,t,m] (bf16, MFMA); (3) out = Y @ BT^T with
//       fused bias + residual + relu epilogue (m97-style 128x128 MFMA GEMM).

typedef short bs8 __attribute__((ext_vector_type(8)));   // 8 x bf16 fragment
typedef float f32x4 __attribute__((ext_vector_type(4))); // MFMA accumulator

#define NB   16
#define NC   64
#define NT   48
#define NN   1024
#define NKS  3
#define KDIM 3072  // NKS * NN

// f32 -> bf16 round-to-nearest-even (finite inputs only)
__device__ __forceinline__ short f2bs(float f) {
  uint32_t u = __builtin_bit_cast(uint32_t, f);
  u = (u + 0x7FFFu + ((u >> 16) & 1u)) >> 16;
  return (short)u;
}

__device__ __forceinline__ void gload16(const void* g, void* l) {
  __builtin_amdgcn_global_load_lds(
      (const __attribute__((address_space(1))) void*)g,
      (__attribute__((address_space(3))) void*)l, 16, 0, 0);
}

// ---------------- prep: BT[n][k*NN+m] = bf16(Lk[k][n][m]) -------------------
__global__ __launch_bounds__(256) void k_prep_bt(const float* __restrict__ Lk,
                                                 short* __restrict__ BT) {
  int gid = blockIdx.x * 256 + threadIdx.x;  // 786432 threads, 4 elems each
  int e = gid * 4;
  int k = e >> 20;
  int rem = e & 1048575;
  int n = rem >> 10;
  int m = rem & 1023;
  float4 v = *reinterpret_cast<const float4*>(Lk + e);
  union { short s[4]; uint64_t u; } p;
  p.s[0] = f2bs(v.x); p.s[1] = f2bs(v.y); p.s[2] = f2bs(v.z); p.s[3] = f2bs(v.w);
  *reinterpret_cast<uint64_t*>(BT + (size_t)n * KDIM + k * NN + m) = p.u;
}

// ---------------- step1: Y[btl*64+o][k*NN+m] = sum_i th[i,o,k] x[b,i,t,m] ---
// grid: bc*48*4 blocks (4 m-tiles of 256), 256 threads (4 waves, 64 m each).
// A-operand (theta^T) from padded LDS; B-operand (x) built from per-lane
// scalar global loads (i is the slow axis of x -> no LDS transpose needed).
__global__ __launch_bounds__(256) void k_step1(const float* __restrict__ x,
                                               const float* __restrict__ theta,
                                               short* __restrict__ Y, int b0) {
  __shared__ __align__(16) short th[NKS * 64 * 72];  // [k][o][i] padded 64->72
  int tid = threadIdx.x;
  for (int idx = tid; idx < NC * NC * NKS; idx += 256) {
    int i = idx / (NC * NKS);
    int r = idx - i * (NC * NKS);
    int o = r / NKS;
    int k = r - o * NKS;
    th[(k * 64 + o) * 72 + i] = f2bs(theta[idx]);  // theta[i][o][k]
  }
  __syncthreads();

  int bid = blockIdx.x;
  int mt  = bid & 3;
  int btl = bid >> 2;           // chunk-local (b_l*48 + t)
  int b_l = btl / NT;
  int t   = btl - b_l * NT;
  int b   = b0 + b_l;

  int lane = tid & 63, wave = tid >> 6;
  int l15 = lane & 15, lg = lane >> 4;
  const float* xb = x + (size_t)b * (NC * NT * NN) + (size_t)t * NN;
  int m0 = mt * 256 + wave * 64;
  size_t yrow0 = (size_t)btl * 64;

  for (int ni = 0; ni < 4; ++ni) {
    int mcol = m0 + ni * 16 + l15;
    float xv[16];
#pragma unroll
    for (int j = 0; j < 16; ++j) {          // i = (j>>3)*32 + lg*8 + (j&7)
      int i = ((j >> 3) << 5) + lg * 8 + (j & 7);
      xv[j] = xb[(size_t)i * (NT * NN) + mcol];
    }
    f32x4 acc[3][4];
#pragma unroll
    for (int k = 0; k < 3; ++k)
#pragma unroll
      for (int mi = 0; mi < 4; ++mi)
        acc[k][mi] = (f32x4){0.f, 0.f, 0.f, 0.f};

#pragma unroll
    for (int ks = 0; ks < 2; ++ks) {
      bs8 bfrag;
#pragma unroll
      for (int j = 0; j < 8; ++j) bfrag[j] = f2bs(xv[ks * 8 + j]);
#pragma unroll
      for (int mi = 0; mi < 4; ++mi) {
#pragma unroll
        for (int k = 0; k < 3; ++k) {
          const bs8* ap = reinterpret_cast<const bs8*>(
              &th[(k * 64 + mi * 16 + l15) * 72 + ks * 32 + lg * 8]);
          acc[k][mi] = __builtin_amdgcn_mfma_f32_16x16x32_bf16(
              *ap, bfrag, acc[k][mi], 0, 0, 0);
        }
      }
    }
    // write Y (bf16): row = btl*64 + o, col = k*NN + m
#pragma unroll
    for (int k = 0; k < 3; ++k)
#pragma unroll
      for (int mi = 0; mi < 4; ++mi)
#pragma unroll
        for (int q = 0; q < 4; ++q) {
          int o = mi * 16 + lg * 4 + q;     // D-layout: row=(lane>>4)*4+q
          Y[(yrow0 + o) * KDIM + k * NN + mcol] = f2bs(acc[k][mi][q]);
        }
  }
}

// ---------------- big GEMM: C = Y @ BT^T, fused bias+residual+relu ----------
// m97 structure: 128x128 tile, BK=64, 4 waves (2x2), global_load_lds w16.
__global__ __launch_bounds__(256) void k_gemm(const short* __restrict__ Y,
                                              const short* __restrict__ BT,
                                              const float* __restrict__ x,
                                              const float* __restrict__ bias,
                                              float* __restrict__ out,
                                              int b0, int nwg) {
  __shared__ __align__(16) short Al[128 * 64];
  __shared__ __align__(16) short Bl[128 * 64];

  int bid = blockIdx.x;
  int cpx = nwg >> 3;                       // nwg % 8 == 0 -> bijective
  int swz = (bid & 7) * cpx + (bid >> 3);   // XCD-aware swizzle
  int colb = swz & 7;
  int rowb = swz >> 3;

  int tid = threadIdx.x;
  int lane = tid & 63, wave = tid >> 6;
  int wr = wave >> 1, wc = wave & 1;
  int l15 = lane & 15, lg = lane >> 4;
  int row0 = rowb * 128, col0 = colb * 128;

  f32x4 acc[4][4];
#pragma unroll
  for (int mi = 0; mi < 4; ++mi)
#pragma unroll
    for (int ni = 0; ni < 4; ++ni) acc[mi][ni] = (f32x4){0.f, 0.f, 0.f, 0.f};

  for (int kt = 0; kt < KDIM / 64; ++kt) {
    int kk = kt * 64;
#pragma unroll
    for (int c = 0; c < 4; ++c) {
      int idx8 = (c * 4 + wave) * 64 + lane;
      int r = idx8 >> 3, c8 = idx8 & 7;
      gload16(Y + (size_t)(row0 + r) * KDIM + kk + c8 * 8,
              &Al[(c * 4 + wave) * 512]);
      gload16(BT + (size_t)(col0 + r) * KDIM + kk + c8 * 8,
              &Bl[(c * 4 + wave) * 512]);
    }
    __syncthreads();
#pragma unroll
    for (int ks = 0; ks < 2; ++ks) {
      bs8 af[4], bf[4];
#pragma unroll
      for (int mi = 0; mi < 4; ++mi)
        af[mi] = *reinterpret_cast<const bs8*>(
            &Al[(wr * 64 + mi * 16 + l15) * 64 + ks * 32 + lg * 8]);
#pragma unroll
      for (int ni = 0; ni < 4; ++ni)
        bf[ni] = *reinterpret_cast<const bs8*>(
            &Bl[(wc * 64 + ni * 16 + l15) * 64 + ks * 32 + lg * 8]);
#pragma unroll
      for (int mi = 0; mi < 4; ++mi)
#pragma unroll
        for (int ni = 0; ni < 4; ++ni)
          acc[mi][ni] = __builtin_amdgcn_mfma_f32_16x16x32_bf16(
              af[mi], bf[ni], acc[mi][ni], 0, 0, 0);
    }
    __syncthreads();
  }

  // epilogue: r(local) -> (b, o, t); out = relu(acc + bias[o] + x)
#pragma unroll
  for (int mi = 0; mi < 4; ++mi) {
#pragma unroll
    for (int q = 0; q < 4; ++q) {
      int r = row0 + wr * 64 + mi * 16 + lg * 4 + q;  // chunk-local row
      int o = r & 63;
      int btl = r >> 6;
      int t = btl % NT;
      int bb = b0 + btl / NT;
      float bo = bias[o];
      size_t obase = ((size_t)(bb * 64 + o) * NT + t) * NN;
#pragma unroll
      for (int ni = 0; ni < 4; ++ni) {
        int n = col0 + wc * 64 + ni * 16 + l15;
        size_t oidx = obase + n;
        float v = acc[mi][ni][q] + bo + x[oidx];
        out[oidx] = v > 0.f ? v : 0.f;
      }
    }
  }
}

extern "C" void kernel_launch(void* const* d_in, const int* in_sizes, int n_in,
                              void* d_out, int out_size, void* d_ws, size_t ws_size,
                              hipStream_t stream) {
  const float* x     = (const float*)d_in[0];
  const float* Lk    = (const float*)d_in[1];
  const float* theta = (const float*)d_in[2];
  const float* bias  = (const float*)d_in[3];
  float* out = (float*)d_out;

  char* ws = (char*)d_ws;
  short* BT = (short*)ws;                         // 6.29 MB
  short* Y  = (short*)(ws + (size_t)(8u << 20));  // up to 302 MB
  size_t avail = ws_size > ((size_t)8u << 20) ? ws_size - ((size_t)8u << 20) : 0;
  size_t perB = (size_t)NT * NC * KDIM * 2;       // 18,874,368 B per batch-row
  int bc = 16;
  while (bc > 1 && (size_t)bc * perB > avail) bc >>= 1;  // chunk over b if needed

  k_prep_bt<<<dim3(3072), dim3(256), 0, stream>>>(Lk, BT);
  for (int b0 = 0; b0 < NB; b0 += bc) {
    int nwg = bc * 192;  // step1: bc*48*4; gemm: (bc*3072/128)*8
    k_step1<<<dim3(nwg), dim3(256), 0, stream>>>(x, theta, Y, b0);
    k_gemm<<<dim3(nwg), dim3(256), 0, stream>>>(Y, BT, x, bias, out, b0, nwg);
  }
}

// Round 2
// 639.615 us; speedup vs baseline: 1.2763x; 1.2763x over previous
//
#include <hip/hip_runtime.h>
#include <hip/hip_bf16.h>
#include <stdint.h>

// SpatioConvLayer: out = relu(x + b + einsum('iok,knm,bitm->botn', theta, Lk, x))
// (1) BT[n][k*1024+m] = bf16(Lk[k][n][m]); (2) Y[(b*48+t)*64+o][k*1024+m]
//     = sum_i theta[i,o,k] * x[b,i,t,m] (bf16, MFMA); (3) out = Y @ BT^T with
//     fused bias + residual + relu. Step (3) = 256x256x64 8-phase pipeline
//     (T1 XCD swizzle + T2 LDS XOR swizzle + T3/T4 counted vmcnt + T5 setprio).

typedef short bs8 __attribute__((ext_vector_type(8)));   // 8 x bf16 fragment
typedef float f32x4 __attribute__((ext_vector_type(4))); // MFMA accumulator

#define NB   16
#define NC   64
#define NT   48
#define NN   1024
#define NKS  3
#define KDIM 3072  // NKS * NN
#define KT   48    // KDIM / 64 K-tiles

// f32 -> bf16 round-to-nearest-even (finite inputs only)
__device__ __forceinline__ short f2bs(float f) {
  uint32_t u = __builtin_bit_cast(uint32_t, f);
  u = (u + 0x7FFFu + ((u >> 16) & 1u)) >> 16;
  return (short)u;
}

__device__ __forceinline__ void gload16(const void* g, void* l) {
  __builtin_amdgcn_global_load_lds(
      (const __attribute__((address_space(1))) void*)g,
      (__attribute__((address_space(3))) void*)l, 16, 0, 0);
}

// ---------------- prep: BT[n][k*NN+m] = bf16(Lk[k][n][m]) -------------------
__global__ __launch_bounds__(256) void k_prep_bt(const float* __restrict__ Lk,
                                                 short* __restrict__ BT) {
  int gid = blockIdx.x * 256 + threadIdx.x;
  int e = gid * 4;
  int k = e >> 20;
  int rem = e & 1048575;
  int n = rem >> 10;
  int m = rem & 1023;
  float4 v = *reinterpret_cast<const float4*>(Lk + e);
  union { short s[4]; uint64_t u; } p;
  p.s[0] = f2bs(v.x); p.s[1] = f2bs(v.y); p.s[2] = f2bs(v.z); p.s[3] = f2bs(v.w);
  *reinterpret_cast<uint64_t*>(BT + (size_t)n * KDIM + k * NN + m) = p.u;
}

// ---------------- step1: Y[btl*64+o][k*NN+m] = sum_i th[i,o,k] x[b,i,t,m] ---
__global__ __launch_bounds__(256) void k_step1(const float* __restrict__ x,
                                               const float* __restrict__ theta,
                                               short* __restrict__ Y, int b0) {
  __shared__ __align__(16) short th[NKS * 64 * 72];  // [k][o][i] padded 64->72
  int tid = threadIdx.x;
  for (int idx = tid; idx < NC * NC * NKS; idx += 256) {
    int i = idx / (NC * NKS);
    int r = idx - i * (NC * NKS);
    int o = r / NKS;
    int k = r - o * NKS;
    th[(k * 64 + o) * 72 + i] = f2bs(theta[idx]);  // theta[i][o][k]
  }
  __syncthreads();

  int bid = blockIdx.x;
  int mt  = bid & 3;
  int btl = bid >> 2;
  int b_l = btl / NT;
  int t   = btl - b_l * NT;
  int b   = b0 + b_l;

  int lane = tid & 63, wave = tid >> 6;
  int l15 = lane & 15, lg = lane >> 4;
  const float* xb = x + (size_t)b * (NC * NT * NN) + (size_t)t * NN;
  int m0 = mt * 256 + wave * 64;
  size_t yrow0 = (size_t)btl * 64;

  for (int ni = 0; ni < 4; ++ni) {
    int mcol = m0 + ni * 16 + l15;
    float xv[16];
#pragma unroll
    for (int j = 0; j < 16; ++j) {
      int i = ((j >> 3) << 5) + lg * 8 + (j & 7);
      xv[j] = xb[(size_t)i * (NT * NN) + mcol];
    }
    f32x4 acc[3][4];
#pragma unroll
    for (int k = 0; k < 3; ++k)
#pragma unroll
      for (int mi = 0; mi < 4; ++mi)
        acc[k][mi] = (f32x4){0.f, 0.f, 0.f, 0.f};

#pragma unroll
    for (int ks = 0; ks < 2; ++ks) {
      bs8 bfrag;
#pragma unroll
      for (int j = 0; j < 8; ++j) bfrag[j] = f2bs(xv[ks * 8 + j]);
#pragma unroll
      for (int mi = 0; mi < 4; ++mi) {
#pragma unroll
        for (int k = 0; k < 3; ++k) {
          const bs8* ap = reinterpret_cast<const bs8*>(
              &th[(k * 64 + mi * 16 + l15) * 72 + ks * 32 + lg * 8]);
          acc[k][mi] = __builtin_amdgcn_mfma_f32_16x16x32_bf16(
              *ap, bfrag, acc[k][mi], 0, 0, 0);
        }
      }
    }
#pragma unroll
    for (int k = 0; k < 3; ++k)
#pragma unroll
      for (int mi = 0; mi < 4; ++mi)
#pragma unroll
        for (int q = 0; q < 4; ++q) {
          int o = mi * 16 + lg * 4 + q;
          Y[(yrow0 + o) * KDIM + k * NN + mcol] = f2bs(acc[k][mi][q]);
        }
  }
}

// ---------------- big GEMM: C = Y @ BT^T, 256^2 8-phase, fused epilogue -----
// 8 waves (2M x 4N, strided frag ownership): wave wr owns abs M-frags 2j+wr,
// wave wc owns abs N-frags 4i+wc. Phase (QM,QN) computes M-frags [8QM,8QM+8) x
// N-frags [8QN,8QN+8) -> touches exactly A-half QM and B-half QN.
// Half lifetime within a K-tile: A0:{ph0,ph1} A1:{ph2,ph3} B0:{ph0,ph2}
// B1:{ph1,ph3}. Stage schedule (1 half-tile per phase, 2 gload16/thread):
//   ph0: A1(t+1)->buf^1   ph1: B1(t+1)->buf^1   (other buf: prev tile done)
//   ph2: A0(t+2)->buf     (A0 slot dead after ph1's barrier)
//   ph3: B0(t+2)->buf     (B0 slot dead after ph2's barrier)
// vmcnt(4) at tile end leaves only {A0,B0}(t+2) in flight => tile t+1 fully
// staged behind the barrier. Tail: t>=KT-2 drains vmcnt(0).
// T2 swizzle: LDS byte ^= (row&7)<<4, applied as source-chunk permute on the
// staging side (c8 ^= row&7) and XOR on the ds_read side (involution).

__device__ __forceinline__ void stage_half(const short* __restrict__ src,
                                           short* lds, int h, int tid) {
  int wave = tid >> 6;
#pragma unroll
  for (int r = 0; r < 2; ++r) {
    int idx = h * 1024 + r * 512 + tid;
    int row = idx >> 3, c8 = idx & 7;
    int c8s = c8 ^ (row & 7);                     // inverse-swizzled source
    gload16(src + (size_t)row * KDIM + c8s * 8,
            lds + (h * 1024 + r * 512 + wave * 64) * 8);  // wave-uniform base
  }
}

#define BARRIER()                              \
  __builtin_amdgcn_sched_barrier(0);           \
  __builtin_amdgcn_s_barrier();                \
  __builtin_amdgcn_sched_barrier(0);

#define PHASE(QM, QN, STAGE, ENDW)                                          \
  {                                                                         \
    bs8 af[4][2], bf[2][2];                                                 \
    _Pragma("unroll") for (int f = 0; f < 2; ++f)                           \
      _Pragma("unroll") for (int ks = 0; ks < 2; ++ks) {                    \
        int rw = (8 * QN + 4 * f + wc) * 16 + l15;                          \
        bf[f][ks] = *(const bs8*)&BL[p * 16384 + rw * 64 +                  \
                      ((ks * 32 + lg * 8) ^ ((rw & 7) << 3))];              \
      }                                                                     \
    _Pragma("unroll") for (int e = 0; e < 4; ++e)                           \
      _Pragma("unroll") for (int ks = 0; ks < 2; ++ks) {                    \
        int rw = (8 * QM + 2 * e + wr) * 16 + l15;                          \
        af[e][ks] = *(const bs8*)&AL[p * 16384 + rw * 64 +                  \
                      ((ks * 32 + lg * 8) ^ ((rw & 7) << 3))];              \
      }                                                                     \
    STAGE;                                                                  \
    BARRIER();                                                              \
    __builtin_amdgcn_s_setprio(1);                                          \
    _Pragma("unroll") for (int e = 0; e < 4; ++e)                           \
      _Pragma("unroll") for (int f = 0; f < 2; ++f)                         \
        _Pragma("unroll") for (int ks = 0; ks < 2; ++ks)                    \
          acc[4 * QM + e][2 * QN + f] =                                     \
              __builtin_amdgcn_mfma_f32_16x16x32_bf16(                      \
                  af[e][ks], bf[f][ks], acc[4 * QM + e][2 * QN + f], 0, 0, 0); \
    __builtin_amdgcn_s_setprio(0);                                          \
    ENDW;                                                                   \
    BARRIER();                                                              \
  }

__global__ __launch_bounds__(512, 2) void k_gemm(const short* __restrict__ Y,
                                                 const short* __restrict__ BT,
                                                 const float* __restrict__ x,
                                                 const float* __restrict__ bias,
                                                 float* __restrict__ out,
                                                 int b0, int nwg) {
  __shared__ __align__(16) short AL[2 * 16384];  // [buf][256][64] 64 KiB
  __shared__ __align__(16) short BL[2 * 16384];  // [buf][256][64] 64 KiB

  int bid = blockIdx.x;
  int cpx = nwg >> 3;                        // nwg % 8 == 0 -> bijective
  int swz = (bid & 7) * cpx + (bid >> 3);    // XCD-aware swizzle
  int colb = swz & 3;                        // 4 col-blocks (N=1024/256)
  int rowb = swz >> 2;

  int tid = threadIdx.x;
  int lane = tid & 63, wave = tid >> 6;
  int wr = wave >> 2, wc = wave & 3;         // 2M x 4N waves
  int l15 = lane & 15, lg = lane >> 4;
  int row0 = rowb * 256, col0 = colb * 256;

  const short* Yb  = Y  + (size_t)row0 * KDIM;
  const short* BTb = BT + (size_t)col0 * KDIM;

  f32x4 acc[8][4];
#pragma unroll
  for (int j = 0; j < 8; ++j)
#pragma unroll
    for (int i = 0; i < 4; ++i) acc[j][i] = (f32x4){0.f, 0.f, 0.f, 0.f};

  // prologue: tile0 (4 halves) -> buf0; A0,B0 of tile1 -> buf1
  stage_half(Yb,        AL,         0, tid);
  stage_half(Yb,        AL,         1, tid);
  stage_half(BTb,       BL,         0, tid);
  stage_half(BTb,       BL,         1, tid);
  stage_half(Yb + 64,   AL + 16384, 0, tid);
  stage_half(BTb + 64,  BL + 16384, 0, tid);
  asm volatile("s_waitcnt vmcnt(4)" ::: "memory");  // tile0's 8 loads done
  BARRIER();

#pragma unroll 2
  for (int t = 0; t < KT; ++t) {
    int p = t & 1;
    const short* Y1 = Yb + (t + 1) * 64;
    const short* B1 = BTb + (t + 1) * 64;
    const short* Y2 = Yb + (t + 2) * 64;
    const short* B2 = BTb + (t + 2) * 64;
    PHASE(0, 0, if (t < KT - 1) stage_half(Y1, AL + (p ^ 1) * 16384, 1, tid), )
    PHASE(0, 1, if (t < KT - 1) stage_half(B1, BL + (p ^ 1) * 16384, 1, tid), )
    PHASE(1, 0, if (t < KT - 2) stage_half(Y2, AL + p * 16384, 0, tid), )
    PHASE(1, 1, if (t < KT - 2) stage_half(B2, BL + p * 16384, 0, tid),
          if (t < KT - 2) { asm volatile("s_waitcnt vmcnt(4)" ::: "memory"); }
          else            { asm volatile("s_waitcnt vmcnt(0)" ::: "memory"); })
  }

  // epilogue: out = relu(acc + bias[o] + x); abs M-frag 2j+wr, N-frag 4i+wc
#pragma unroll
  for (int j = 0; j < 8; ++j) {
#pragma unroll
    for (int q = 0; q < 4; ++q) {
      int r = row0 + (2 * j + wr) * 16 + lg * 4 + q;  // chunk-local row
      int o = r & 63;
      int btl = r >> 6;
      int tt = btl % NT;
      int bb = b0 + btl / NT;
      float bo = bias[o];
      size_t obase = ((size_t)(bb * 64 + o) * NT + tt) * NN;
#pragma unroll
      for (int i = 0; i < 4; ++i) {
        int n = col0 + (4 * i + wc) * 16 + l15;
        size_t oidx = obase + n;
        float v = acc[j][i][q] + bo + x[oidx];
        out[oidx] = v > 0.f ? v : 0.f;
      }
    }
  }
}

extern "C" void kernel_launch(void* const* d_in, const int* in_sizes, int n_in,
                              void* d_out, int out_size, void* d_ws, size_t ws_size,
                              hipStream_t stream) {
  const float* x     = (const float*)d_in[0];
  const float* Lk    = (const float*)d_in[1];
  const float* theta = (const float*)d_in[2];
  const float* bias  = (const float*)d_in[3];
  float* out = (float*)d_out;

  char* ws = (char*)d_ws;
  short* BT = (short*)ws;                         // 6.29 MB
  short* Y  = (short*)(ws + (size_t)(8u << 20));  // up to 302 MB
  size_t avail = ws_size > ((size_t)8u << 20) ? ws_size - ((size_t)8u << 20) : 0;
  size_t perB = (size_t)NT * NC * KDIM * 2;       // 18,874,368 B per batch-row
  int bc = 16;
  while (bc > 1 && (size_t)bc * perB > avail) bc >>= 1;  // chunk over b if needed

  k_prep_bt<<<dim3(3072), dim3(256), 0, stream>>>(Lk, BT);
  for (int b0 = 0; b0 < NB; b0 += bc) {
    k_step1<<<dim3(bc * 192), dim3(256), 0, stream>>>(x, theta, Y, b0);
    int nwg = bc * 48;  // (bc*3072/256 rowb) * 4 colb, divisible by 8
    k_gemm<<<dim3(nwg), dim3(512), 0, stream>>>(Y, BT, x, bias, out, b0, nwg);
  }
}

// Round 3
// 571.753 us; speedup vs baseline: 1.4278x; 1.1187x over previous
//
#include <hip/hip_runtime.h>
#include <hip/hip_bf16.h>
#include <stdint.h>

// SpatioConvLayer: out = relu(x + b + einsum('iok,knm,bitm->botn', theta, Lk, x))
// (1) BT[n][k*1024+m] = bf16(Lk[k][n][m]); (2) Y[(b*48+t)*64+o][k*1024+m]
//     = sum_i theta[i,o,k] * x[b,i,t,m] (bf16, MFMA); (3) out = Y @ BT^T with
//     fused bias + residual + relu. Step (3) = 256x256x64 8-phase pipeline
//     (T1 XCD swizzle + T2 LDS XOR swizzle + T3/T4 counted vmcnt + T5 setprio).
// R3: ks-outer MFMA order (dep distance 8, was 1) + fragment reuse across
//     phases (24 ds_read/tile/wave, was 48) -> LDS floor below MFMA floor.

typedef short bs8 __attribute__((ext_vector_type(8)));   // 8 x bf16 fragment
typedef float f32x4 __attribute__((ext_vector_type(4))); // MFMA accumulator

#define NB   16
#define NC   64
#define NT   48
#define NN   1024
#define NKS  3
#define KDIM 3072  // NKS * NN
#define KT   48    // KDIM / 64 K-tiles

// f32 -> bf16 round-to-nearest-even (finite inputs only)
__device__ __forceinline__ short f2bs(float f) {
  uint32_t u = __builtin_bit_cast(uint32_t, f);
  u = (u + 0x7FFFu + ((u >> 16) & 1u)) >> 16;
  return (short)u;
}

__device__ __forceinline__ void gload16(const void* g, void* l) {
  __builtin_amdgcn_global_load_lds(
      (const __attribute__((address_space(1))) void*)g,
      (__attribute__((address_space(3))) void*)l, 16, 0, 0);
}

// ---------------- prep: BT[n][k*NN+m] = bf16(Lk[k][n][m]) -------------------
__global__ __launch_bounds__(256) void k_prep_bt(const float* __restrict__ Lk,
                                                 short* __restrict__ BT) {
  int gid = blockIdx.x * 256 + threadIdx.x;
  int e = gid * 4;
  int k = e >> 20;
  int rem = e & 1048575;
  int n = rem >> 10;
  int m = rem & 1023;
  float4 v = *reinterpret_cast<const float4*>(Lk + e);
  union { short s[4]; uint64_t u; } p;
  p.s[0] = f2bs(v.x); p.s[1] = f2bs(v.y); p.s[2] = f2bs(v.z); p.s[3] = f2bs(v.w);
  *reinterpret_cast<uint64_t*>(BT + (size_t)n * KDIM + k * NN + m) = p.u;
}

// ---------------- step1: Y[btl*64+o][k*NN+m] = sum_i th[i,o,k] x[b,i,t,m] ---
__global__ __launch_bounds__(256) void k_step1(const float* __restrict__ x,
                                               const float* __restrict__ theta,
                                               short* __restrict__ Y, int b0) {
  __shared__ __align__(16) short th[NKS * 64 * 72];  // [k][o][i] padded 64->72
  int tid = threadIdx.x;
  for (int idx = tid; idx < NC * NC * NKS; idx += 256) {
    int i = idx / (NC * NKS);
    int r = idx - i * (NC * NKS);
    int o = r / NKS;
    int k = r - o * NKS;
    th[(k * 64 + o) * 72 + i] = f2bs(theta[idx]);  // theta[i][o][k]
  }
  __syncthreads();

  int bid = blockIdx.x;
  int mt  = bid & 3;
  int btl = bid >> 2;
  int b_l = btl / NT;
  int t   = btl - b_l * NT;
  int b   = b0 + b_l;

  int lane = tid & 63, wave = tid >> 6;
  int l15 = lane & 15, lg = lane >> 4;
  const float* xb = x + (size_t)b * (NC * NT * NN) + (size_t)t * NN;
  int m0 = mt * 256 + wave * 64;
  size_t yrow0 = (size_t)btl * 64;

  for (int ni = 0; ni < 4; ++ni) {
    int mcol = m0 + ni * 16 + l15;
    float xv[16];
#pragma unroll
    for (int j = 0; j < 16; ++j) {
      int i = ((j >> 3) << 5) + lg * 8 + (j & 7);
      xv[j] = xb[(size_t)i * (NT * NN) + mcol];
    }
    f32x4 acc[3][4];
#pragma unroll
    for (int k = 0; k < 3; ++k)
#pragma unroll
      for (int mi = 0; mi < 4; ++mi)
        acc[k][mi] = (f32x4){0.f, 0.f, 0.f, 0.f};

#pragma unroll
    for (int ks = 0; ks < 2; ++ks) {
      bs8 bfrag;
#pragma unroll
      for (int j = 0; j < 8; ++j) bfrag[j] = f2bs(xv[ks * 8 + j]);
#pragma unroll
      for (int mi = 0; mi < 4; ++mi) {
#pragma unroll
        for (int k = 0; k < 3; ++k) {
          const bs8* ap = reinterpret_cast<const bs8*>(
              &th[(k * 64 + mi * 16 + l15) * 72 + ks * 32 + lg * 8]);
          acc[k][mi] = __builtin_amdgcn_mfma_f32_16x16x32_bf16(
              *ap, bfrag, acc[k][mi], 0, 0, 0);
        }
      }
    }
#pragma unroll
    for (int k = 0; k < 3; ++k)
#pragma unroll
      for (int mi = 0; mi < 4; ++mi)
#pragma unroll
        for (int q = 0; q < 4; ++q) {
          int o = mi * 16 + lg * 4 + q;
          Y[(yrow0 + o) * KDIM + k * NN + mcol] = f2bs(acc[k][mi][q]);
        }
  }
}

// ---------------- big GEMM: C = Y @ BT^T, 256^2 8-phase, fused epilogue -----
// 8 waves (2M x 4N, strided frag ownership): wave wr owns abs M-frags 2j+wr,
// wave wc owns abs N-frags 4i+wc. Phase visit order (QM,QN) =
// (0,0)->(0,1)->(1,1)->(1,0) so fragments are reused from registers:
//   P0: read A0(8) + B0(4); P1: read B1(4) [B0 stays live];
//   P2: read A1(8) [overwrites af after last use at P1]; P3: no reads.
// Half lifetime (ds_read) in a K-tile: A0:{P0} A1:{P2} B0:{P0} B1:{P1}.
// Stage schedule (1 half-tile per phase, 2 gload16/thread/wave):
//   P0: A1(t+1)->buf^1   P1: B1(t+1)->buf^1
//   P2: A0(t+2)->buf  (A0(t) slot dead after P0's barriers)
//   P3: B0(t+2)->buf  (B0(t) slot dead after P0's barriers)
// vmcnt(4) at tile end leaves only {A0,B0}(t+2) in flight => tile t+1 fully
// staged behind the barrier. Tail: t>=KT-2 drains vmcnt(0).
// T2 swizzle: LDS byte ^= (row&7)<<4, applied as source-chunk permute on the
// staging side (c8 ^= row&7) and XOR on the ds_read side (involution).

__device__ __forceinline__ void stage_half(const short* __restrict__ src,
                                           short* lds, int h, int tid) {
  int wave = tid >> 6;
#pragma unroll
  for (int r = 0; r < 2; ++r) {
    int idx = h * 1024 + r * 512 + tid;
    int row = idx >> 3, c8 = idx & 7;
    int c8s = c8 ^ (row & 7);                     // inverse-swizzled source
    gload16(src + (size_t)row * KDIM + c8s * 8,
            lds + (h * 1024 + r * 512 + wave * 64) * 8);  // wave-uniform base
  }
}

#define BARRIER()                              \
  __builtin_amdgcn_sched_barrier(0);           \
  __builtin_amdgcn_s_barrier();                \
  __builtin_amdgcn_sched_barrier(0);

#define READ_A(QM)                                                        \
  _Pragma("unroll") for (int e = 0; e < 4; ++e)                           \
    _Pragma("unroll") for (int ks = 0; ks < 2; ++ks) {                    \
      int rw = (8 * (QM) + 2 * e + wr) * 16 + l15;                        \
      af[e][ks] = *(const bs8*)&AL[p * 16384 + rw * 64 +                  \
                    ((ks * 32 + lg * 8) ^ ((rw & 7) << 3))];              \
    }

#define READ_B(BF, QN)                                                    \
  _Pragma("unroll") for (int f = 0; f < 2; ++f)                           \
    _Pragma("unroll") for (int ks = 0; ks < 2; ++ks) {                    \
      int rw = (8 * (QN) + 4 * f + wc) * 16 + l15;                        \
      BF[f][ks] = *(const bs8*)&BL[p * 16384 + rw * 64 +                  \
                    ((ks * 32 + lg * 8) ^ ((rw & 7) << 3))];              \
    }

// ks-outer: dependent MFMAs on the same acc are 8 apart (was back-to-back)
#define COMPUTE(QM, BF, QN)                                                 \
  __builtin_amdgcn_s_setprio(1);                                            \
  _Pragma("unroll") for (int ks = 0; ks < 2; ++ks)                          \
    _Pragma("unroll") for (int e = 0; e < 4; ++e)                           \
      _Pragma("unroll") for (int f = 0; f < 2; ++f)                         \
        acc[4 * (QM) + e][2 * (QN) + f] =                                   \
            __builtin_amdgcn_mfma_f32_16x16x32_bf16(                        \
                af[e][ks], BF[f][ks], acc[4 * (QM) + e][2 * (QN) + f],      \
                0, 0, 0);                                                   \
  __builtin_amdgcn_s_setprio(0);

__global__ __launch_bounds__(512, 2) void k_gemm(const short* __restrict__ Y,
                                                 const short* __restrict__ BT,
                                                 const float* __restrict__ x,
                                                 const float* __restrict__ bias,
                                                 float* __restrict__ out,
                                                 int b0, int nwg) {
  __shared__ __align__(16) short AL[2 * 16384];  // [buf][256][64] 64 KiB
  __shared__ __align__(16) short BL[2 * 16384];  // [buf][256][64] 64 KiB

  int bid = blockIdx.x;
  int cpx = nwg >> 3;                        // nwg % 8 == 0 -> bijective
  int swz = (bid & 7) * cpx + (bid >> 3);    // XCD-aware swizzle
  int colb = swz & 3;                        // 4 col-blocks (N=1024/256)
  int rowb = swz >> 2;

  int tid = threadIdx.x;
  int lane = tid & 63, wave = tid >> 6;
  int wr = wave >> 2, wc = wave & 3;         // 2M x 4N waves
  int l15 = lane & 15, lg = lane >> 4;
  int row0 = rowb * 256, col0 = colb * 256;

  const short* Yb  = Y  + (size_t)row0 * KDIM;
  const short* BTb = BT + (size_t)col0 * KDIM;

  f32x4 acc[8][4];
#pragma unroll
  for (int j = 0; j < 8; ++j)
#pragma unroll
    for (int i = 0; i < 4; ++i) acc[j][i] = (f32x4){0.f, 0.f, 0.f, 0.f};

  // prologue: tile0 (4 halves) -> buf0; A0,B0 of tile1 -> buf1
  stage_half(Yb,        AL,         0, tid);
  stage_half(Yb,        AL,         1, tid);
  stage_half(BTb,       BL,         0, tid);
  stage_half(BTb,       BL,         1, tid);
  stage_half(Yb + 64,   AL + 16384, 0, tid);
  stage_half(BTb + 64,  BL + 16384, 0, tid);
  asm volatile("s_waitcnt vmcnt(4)" ::: "memory");  // tile0's 8 loads done
  BARRIER();

#pragma unroll 2
  for (int t = 0; t < KT; ++t) {
    int p = t & 1;
    const short* Y1 = Yb + (t + 1) * 64;
    const short* B1 = BTb + (t + 1) * 64;
    const short* Y2 = Yb + (t + 2) * 64;
    const short* B2 = BTb + (t + 2) * 64;
    bs8 af[4][2], bf0[2][2], bf1[2][2];

    // P0: (QM0,QN0)
    READ_A(0)
    READ_B(bf0, 0)
    if (t < KT - 1) stage_half(Y1, AL + (p ^ 1) * 16384, 1, tid);
    BARRIER();
    COMPUTE(0, bf0, 0)
    BARRIER();

    // P1: (QM0,QN1)  [af, bf0 stay live]
    READ_B(bf1, 1)
    if (t < KT - 1) stage_half(B1, BL + (p ^ 1) * 16384, 1, tid);
    BARRIER();
    COMPUTE(0, bf1, 1)
    BARRIER();

    // P2: (QM1,QN1)  [af overwritten after last use; bf1 reused]
    READ_A(1)
    if (t < KT - 2) stage_half(Y2, AL + p * 16384, 0, tid);
    BARRIER();
    COMPUTE(1, bf1, 1)
    BARRIER();

    // P3: (QM1,QN0)  [no ds_reads: af=A1, bf0=B0 from registers]
    if (t < KT - 2) stage_half(B2, BL + p * 16384, 0, tid);
    BARRIER();
    COMPUTE(1, bf0, 0)
    if (t < KT - 2) { asm volatile("s_waitcnt vmcnt(4)" ::: "memory"); }
    else            { asm volatile("s_waitcnt vmcnt(0)" ::: "memory"); }
    BARRIER();
  }

  // epilogue: out = relu(acc + bias[o] + x); abs M-frag 2j+wr, N-frag 4i+wc
#pragma unroll
  for (int j = 0; j < 8; ++j) {
#pragma unroll
    for (int q = 0; q < 4; ++q) {
      int r = row0 + (2 * j + wr) * 16 + lg * 4 + q;  // chunk-local row
      int o = r & 63;
      int btl = r >> 6;
      int tt = btl % NT;
      int bb = b0 + btl / NT;
      float bo = bias[o];
      size_t obase = ((size_t)(bb * 64 + o) * NT + tt) * NN;
#pragma unroll
      for (int i = 0; i < 4; ++i) {
        int n = col0 + (4 * i + wc) * 16 + l15;
        size_t oidx = obase + n;
        float v = acc[j][i][q] + bo + x[oidx];
        out[oidx] = v > 0.f ? v : 0.f;
      }
    }
  }
}

extern "C" void kernel_launch(void* const* d_in, const int* in_sizes, int n_in,
                              void* d_out, int out_size, void* d_ws, size_t ws_size,
                              hipStream_t stream) {
  const float* x     = (const float*)d_in[0];
  const float* Lk    = (const float*)d_in[1];
  const float* theta = (const float*)d_in[2];
  const float* bias  = (const float*)d_in[3];
  float* out = (float*)d_out;

  char* ws = (char*)d_ws;
  short* BT = (short*)ws;                         // 6.29 MB
  short* Y  = (short*)(ws + (size_t)(8u << 20));  // up to 302 MB
  size_t avail = ws_size > ((size_t)8u << 20) ? ws_size - ((size_t)8u << 20) : 0;
  size_t perB = (size_t)NT * NC * KDIM * 2;       // 18,874,368 B per batch-row
  int bc = 16;
  while (bc > 1 && (size_t)bc * perB > avail) bc >>= 1;  // chunk over b if needed

  k_prep_bt<<<dim3(3072), dim3(256), 0, stream>>>(Lk, BT);
  for (int b0 = 0; b0 < NB; b0 += bc) {
    k_step1<<<dim3(bc * 192), dim3(256), 0, stream>>>(x, theta, Y, b0);
    int nwg = bc * 48;  // (bc*3072/256 rowb) * 4 colb, divisible by 8
    k_gemm<<<dim3(nwg), dim3(512), 0, stream>>>(Y, BT, x, bias, out, b0, nwg);
  }
}